// Round 7
// baseline (381.315 us; speedup 1.0000x reference)
//
#include <hip/hip_runtime.h>
#include <cstdint>
#include <cstddef>

#define NNODES 50000
#define NPAD   50048      // 782 * 64
#define NEDGES 800000
#define HEADS 4
#define HID 64
#define FDIM 256          // HEADS*HID == IN_DIM == 256
#define NEG_SLOPE 0.2f

typedef short bf16x8 __attribute__((ext_vector_type(8)));
typedef float f32x4  __attribute__((ext_vector_type(4)));

// ---------- helpers ----------
__device__ __forceinline__ float elu_f(float x) {
    return x > 0.0f ? x : expm1f(x);
}
__device__ __forceinline__ float lrelu_f(float x) {
    return x > 0.0f ? x : NEG_SLOPE * x;
}
__device__ __forceinline__ unsigned short f2bf_rn(float x) {
    unsigned u = __float_as_uint(x);
    unsigned r = u + 0x7FFFu + ((u >> 16) & 1u);
    return (unsigned short)(r >> 16);
}
__device__ __forceinline__ void split_bf16(float x, unsigned short& hi, unsigned short& lo) {
    hi = f2bf_rn(x);
    float fhi = __uint_as_float(((unsigned)hi) << 16);
    lo = f2bf_rn(x - fhi);
}

// ---------- fused prep ----------
// blocks [0,32): wconv with LDS transpose (16 k-rows x 256 n per block)
// blocks [32,64): WAL/WAR build: wal[c][k], c in 0..15 (0-3 el heads, 4-7 er heads, 8-15 zero)
// blocks [64, 64+XCONV): x -> bf16 hi/lo planes
// rest: degree count
#define WCONV_BLKS 32
#define WAL_BLKS   32
#define XCONV_BLKS 12512
__global__ __launch_bounds__(256) void prep(const float* __restrict__ x,
                                            unsigned short* __restrict__ abhi,
                                            unsigned short* __restrict__ ablo,
                                            const float* __restrict__ W1,
                                            unsigned short* __restrict__ wt1h,
                                            unsigned short* __restrict__ wt1l,
                                            const float* __restrict__ W2,
                                            unsigned short* __restrict__ wt2h,
                                            unsigned short* __restrict__ wt2l,
                                            const float* __restrict__ al1,
                                            const float* __restrict__ ar1,
                                            const float* __restrict__ al2,
                                            const float* __restrict__ ar2,
                                            unsigned short* __restrict__ we1h,
                                            unsigned short* __restrict__ we1l,
                                            unsigned short* __restrict__ we2h,
                                            unsigned short* __restrict__ we2l,
                                            const int* __restrict__ dst,
                                            int* __restrict__ deg) {
    __shared__ unsigned short wlds[2][16][264];
    int b = blockIdx.x;
    int tid = threadIdx.x;
    if (b < WCONV_BLKS) {
        int mat = b >> 4;
        const float* W = mat ? W2 : W1;
        unsigned short* wth = mat ? wt2h : wt1h;
        unsigned short* wtl = mat ? wt2l : wt1l;
        int k0 = (b & 15) * 16;
        #pragma unroll
        for (int i = 0; i < 16; ++i) {
            int r = i;            // k0+r row, col tid
            unsigned short h, l;
            split_bf16(W[(k0 + r) * 256 + tid], h, l);
            wlds[0][r][tid] = h;
            wlds[1][r][tid] = l;
        }
        __syncthreads();
        // thread n=tid writes 16 contiguous k for its n: wt[n*256 + k0 .. +15]
        unsigned short vh[16], vl[16];
        #pragma unroll
        for (int j = 0; j < 16; ++j) { vh[j] = wlds[0][j][tid]; vl[j] = wlds[1][j][tid]; }
        *(uint4*)(wth + (size_t)tid * 256 + k0)     = *(uint4*)(vh);
        *(uint4*)(wth + (size_t)tid * 256 + k0 + 8) = *(uint4*)(vh + 8);
        *(uint4*)(wtl + (size_t)tid * 256 + k0)     = *(uint4*)(vl);
        *(uint4*)(wtl + (size_t)tid * 256 + k0 + 8) = *(uint4*)(vl + 8);
    } else if (b < WCONV_BLKS + WAL_BLKS) {
        int bb = b - WCONV_BLKS;
        int layer = bb >> 4;
        const float* W  = layer ? W2 : W1;
        const float* al = layer ? al2 : al1;
        const float* ar = layer ? ar2 : ar1;
        unsigned short* weh = layer ? we2h : we1h;
        unsigned short* wel = layer ? we2l : we1l;
        int t = (bb & 15) * 256 + tid;               // 0..4095
        int c = t >> 8, k = t & 255;                 // c: 0..15
        float val = 0.0f;
        if (c < 8) {
            int hh = c & 3;
            const float* av = (c < 4) ? al : ar;     // [4][64] flat
            const float* wr = W + k * 256 + hh * 64;
            #pragma unroll 16
            for (int d = 0; d < 64; ++d) val += wr[d] * av[hh * 64 + d];
        }
        unsigned short h, l;
        split_bf16(val, h, l);
        weh[c * 256 + k] = h;
        wel[c * 256 + k] = l;
    } else if (b < WCONV_BLKS + WAL_BLKS + XCONV_BLKS) {
        int i = (b - WCONV_BLKS - WAL_BLKS) * 256 + tid;   // float4 chunk id
        if (i >= NPAD * 64) return;
        int row = i >> 6;
        float4 v = {0, 0, 0, 0};
        if (row < NNODES) v = ((const float4*)x)[i];
        ushort4 h4, l4;
        split_bf16(v.x, h4.x, l4.x);
        split_bf16(v.y, h4.y, l4.y);
        split_bf16(v.z, h4.z, l4.z);
        split_bf16(v.w, h4.w, l4.w);
        ((ushort4*)abhi)[i] = h4;
        ((ushort4*)ablo)[i] = l4;
    } else {
        int e = (b - WCONV_BLKS - WAL_BLKS - XCONV_BLKS) * 256 + tid;
        if (e < NEDGES) atomicAdd(&deg[dst[e]], 1);
    }
}

// ---------- split-bf16 MFMA GEMM; el/er as 8 folded columns; output = bf16-hi plane ----------
#define CSTR 261
__global__ __launch_bounds__(256, 2) void gemm_mfma(const unsigned short* __restrict__ Ahi,
                                                    const unsigned short* __restrict__ Alo,
                                                    const unsigned short* __restrict__ WThi,
                                                    const unsigned short* __restrict__ WTlo,
                                                    const unsigned short* __restrict__ WEhi,
                                                    const unsigned short* __restrict__ WElo,
                                                    unsigned short* __restrict__ fbh,
                                                    float* __restrict__ el,
                                                    float* __restrict__ er) {
    __shared__ char smem[66816];                     // A: 2x32768B; C: 64x261 f32
    const int tid  = threadIdx.x;
    const int lane = tid & 63;
    const int wave = tid >> 6;
    const int block_row = blockIdx.x * 64;

    // ---- stage A tile (hi+lo, 64 rows x 256 k, XOR-swizzled) ----
    const unsigned short* aplane[2] = {Ahi + (size_t)block_row * 256,
                                       Alo + (size_t)block_row * 256};
    #pragma unroll
    for (int i = 0; i < 16; ++i) {
        int chunk = i * 256 + tid;                   // 16B chunks, 0..4095
        int p   = chunk >> 11;
        int row = (chunk >> 5) & 63;
        int c   = chunk & 31;
        uint4 v = *(const uint4*)(aplane[p] + row * 256 + c * 8);
        int off = p * 32768 + row * 512 + ((c * 16) ^ ((row & 7) << 4));
        *(uint4*)(smem + off) = v;
    }
    __syncthreads();

    // ---- K-loop ----
    f32x4 acc[4][4];
    f32x4 acc_e = (f32x4){0, 0, 0, 0};               // extra el/er tile (m = wave)
    #pragma unroll
    for (int m = 0; m < 4; ++m)
        #pragma unroll
        for (int n = 0; n < 4; ++n)
            acc[m][n] = (f32x4){0, 0, 0, 0};

    const int g = lane >> 4;                         // 0..3
    int arow[4], aswz[4];
    #pragma unroll
    for (int m = 0; m < 4; ++m) {
        int row = m * 16 + (lane & 15);
        arow[m] = row * 512;
        aswz[m] = (row & 7) << 4;
    }
    const unsigned short* wb[2][4];
    #pragma unroll
    for (int n = 0; n < 4; ++n) {
        int col = wave * 64 + n * 16 + (lane & 15);
        wb[0][n] = WThi + col * 256 + g * 8;
        wb[1][n] = WTlo + col * 256 + g * 8;
    }
    const unsigned short* we_h = WEhi + (lane & 15) * 256 + g * 8;
    const unsigned short* we_l = WElo + (lane & 15) * 256 + g * 8;

    #pragma unroll
    for (int t = 0; t < 8; ++t) {
        bf16x8 ah[4], al_[4], wh[4], wl[4];
        int koff = t * 64 + g * 16;
        #pragma unroll
        for (int m = 0; m < 4; ++m) {
            ah[m]  = *(const bf16x8*)(smem + arow[m] + (koff ^ aswz[m]));
            al_[m] = *(const bf16x8*)(smem + 32768 + arow[m] + (koff ^ aswz[m]));
        }
        #pragma unroll
        for (int n = 0; n < 4; ++n) {
            wh[n] = *(const bf16x8*)(wb[0][n] + t * 32);
            wl[n] = *(const bf16x8*)(wb[1][n] + t * 32);
        }
        #pragma unroll
        for (int m = 0; m < 4; ++m)
            #pragma unroll
            for (int n = 0; n < 4; ++n) {
                acc[m][n] = __builtin_amdgcn_mfma_f32_16x16x32_bf16(ah[m],  wh[n], acc[m][n], 0, 0, 0);
                acc[m][n] = __builtin_amdgcn_mfma_f32_16x16x32_bf16(ah[m],  wl[n], acc[m][n], 0, 0, 0);
                acc[m][n] = __builtin_amdgcn_mfma_f32_16x16x32_bf16(al_[m], wh[n], acc[m][n], 0, 0, 0);
            }
        // extra el/er tile: wave w handles m-subtile w
        bf16x8 ahw = (wave == 0) ? ah[0] : (wave == 1) ? ah[1] : (wave == 2) ? ah[2] : ah[3];
        bf16x8 alw = (wave == 0) ? al_[0] : (wave == 1) ? al_[1] : (wave == 2) ? al_[2] : al_[3];
        bf16x8 eh = *(const bf16x8*)(we_h + t * 32);
        bf16x8 el8 = *(const bf16x8*)(we_l + t * 32);
        acc_e = __builtin_amdgcn_mfma_f32_16x16x32_bf16(ahw, eh,  acc_e, 0, 0, 0);
        acc_e = __builtin_amdgcn_mfma_f32_16x16x32_bf16(ahw, el8, acc_e, 0, 0, 0);
        acc_e = __builtin_amdgcn_mfma_f32_16x16x32_bf16(alw, eh,  acc_e, 0, 0, 0);
    }

    // ---- el/er direct store: col (lane&15): 0-3 el heads, 4-7 er heads ----
    {
        int c = lane & 15, rg = lane >> 4;
        if (c < 8) {
            float* dp = (c < 4) ? el : er;
            int hh = c & 3;
            #pragma unroll
            for (int r = 0; r < 4; ++r) {
                int node = block_row + wave * 16 + rg * 4 + r;
                dp[node * 4 + hh] = acc_e[r];
            }
        }
    }

    // ---- epilogue: C -> LDS (row-major [64][261]) ----
    __syncthreads();                                 // A planes dead
    float* C = (float*)smem;
    #pragma unroll
    for (int m = 0; m < 4; ++m) {
        int r0 = m * 16 + g * 4;
        #pragma unroll
        for (int n = 0; n < 4; ++n) {
            int col = wave * 64 + n * 16 + (lane & 15);
            C[(r0 + 0) * CSTR + col] = acc[m][n][0];
            C[(r0 + 1) * CSTR + col] = acc[m][n][1];
            C[(r0 + 2) * CSTR + col] = acc[m][n][2];
            C[(r0 + 3) * CSTR + col] = acc[m][n][3];
        }
    }
    __syncthreads();

    // coalesced bf16-hi feat write: 64 rows x 32 chunks of 16B
    #pragma unroll
    for (int i = 0; i < 8; ++i) {
        int flat = i * 256 + tid;                    // 0..2047
        int r  = flat >> 5;
        int c8 = flat & 31;
        const float* cp = C + r * CSTR + c8 * 8;
        unsigned short us[8];
        #pragma unroll
        for (int k = 0; k < 8; ++k) us[k] = f2bf_rn(cp[k]);
        uint4 pk;
        pk.x = (unsigned)us[0] | ((unsigned)us[1] << 16);
        pk.y = (unsigned)us[2] | ((unsigned)us[3] << 16);
        pk.z = (unsigned)us[4] | ((unsigned)us[5] << 16);
        pk.w = (unsigned)us[6] | ((unsigned)us[7] << 16);
        *(uint4*)(fbh + (size_t)(block_row + r) * FDIM + c8 * 8) = pk;
    }
}

// ---------- CSR build ----------
__global__ __launch_bounds__(256) void scan_block(const int* __restrict__ in,
                                                  int* __restrict__ out,
                                                  int* __restrict__ bsums, int n) {
    int gid = blockIdx.x * 256 + threadIdx.x;
    int v = (gid < n) ? in[gid] : 0;
    int lane = threadIdx.x & 63;
    #pragma unroll
    for (int off = 1; off < 64; off <<= 1) {
        int t = __shfl_up(v, off, 64);
        if (lane >= off) v += t;
    }
    __shared__ int wsum[4];
    int wid = threadIdx.x >> 6;
    if (lane == 63) wsum[wid] = v;
    __syncthreads();
    int add = 0;
    for (int w = 0; w < wid; ++w) add += wsum[w];
    v += add;
    if (gid < n) out[gid] = v;
    if (bsums && threadIdx.x == 255) bsums[blockIdx.x] = v;
}

// final incl[node] = incl_local[node] + (node>=256 ? auxs[node/256-1] : 0)
__device__ __forceinline__ int incl_final(const int* incl, const int* auxs, int node) {
    int v = incl[node];
    if (node >= 256) v += auxs[(node >> 8) - 1];
    return v;
}

__global__ __launch_bounds__(256) void fill_csr(const int* __restrict__ src,
                                                const int* __restrict__ dst,
                                                const int* __restrict__ incl,
                                                const int* __restrict__ auxs,
                                                const int* __restrict__ deg,
                                                int* __restrict__ cursor,
                                                int* __restrict__ csr_src) {
    int e = blockIdx.x * 256 + threadIdx.x;
    if (e >= NEDGES) return;
    int s = src[e], d = dst[e];
    int start = incl_final(incl, auxs, d) - deg[d];
    int pos = start + atomicAdd(&cursor[d], 1);
    csr_src[pos] = s;
}

// ---------- fused per-node softmax + aggregate + bias + ELU, head-pair split ----------
template <int LAYER>
__global__ __launch_bounds__(256, 8) void gat_node(const int* __restrict__ csr_src,
                                                   const int* __restrict__ incl,
                                                   const int* __restrict__ auxs,
                                                   const int* __restrict__ deg,
                                                   const float* __restrict__ el,
                                                   const float* __restrict__ er,
                                                   const unsigned short* __restrict__ fbh,
                                                   const float* __restrict__ bias,
                                                   float* __restrict__ outp,
                                                   unsigned short* __restrict__ ohi,
                                                   unsigned short* __restrict__ olo) {
    __shared__ float alds[4][64][2];
    __shared__ int   slds[4][64];
    int wv   = threadIdx.x >> 6;                 // 0..3
    int node = blockIdx.x * 2 + (wv >> 1);
    int hp   = wv & 1;                           // head-pair
    if (node >= NNODES) return;
    int lane = threadIdx.x & 63;
    int hl   = lane >> 5;                        // head-local 0/1
    int head = hp * 2 + hl;

    int end   = incl_final(incl, auxs, node);
    int dg    = deg[node];
    int start = end - dg;
    float2 r2 = *(const float2*)(er + node * 4 + hp * 2);
    float2 acc = {0, 0};
    const char* fb = (const char*)fbh;
    const int boff = hp * 256 + hl * 128 + (lane & 31) * 4;   // byte off in 512B row

    if (dg <= 64) {
        bool act = lane < dg;
        int s = act ? csr_src[start + lane] : 0;
        float2 l2 = *(const float2*)(el + s * 4 + hp * 2);
        float c0 = act ? lrelu_f(l2.x + r2.x) : -INFINITY;
        float c1 = act ? lrelu_f(l2.y + r2.y) : -INFINITY;
        float m0 = c0, m1 = c1;
        #pragma unroll
        for (int off = 1; off < 64; off <<= 1) {
            m0 = fmaxf(m0, __shfl_xor(m0, off, 64));
            m1 = fmaxf(m1, __shfl_xor(m1, off, 64));
        }
        float p0 = act ? expf(c0 - m0) : 0.0f;
        float p1 = act ? expf(c1 - m1) : 0.0f;
        float s0 = p0, s1 = p1;
        #pragma unroll
        for (int off = 1; off < 64; off <<= 1) {
            s0 += __shfl_xor(s0, off, 64);
            s1 += __shfl_xor(s1, off, 64);
        }
        alds[wv][lane][0] = p0 / s0;
        alds[wv][lane][1] = p1 / s1;
        slds[wv][lane] = s;
        __builtin_amdgcn_wave_barrier();
    } else {
        float m0 = -INFINITY, m1 = -INFINITY;
        for (int i = start + lane; i < end; i += 64) {
            int s = csr_src[i];
            float2 l2 = *(const float2*)(el + s * 4 + hp * 2);
            m0 = fmaxf(m0, lrelu_f(l2.x + r2.x));
            m1 = fmaxf(m1, lrelu_f(l2.y + r2.y));
        }
        #pragma unroll
        for (int off = 1; off < 64; off <<= 1) {
            m0 = fmaxf(m0, __shfl_xor(m0, off, 64));
            m1 = fmaxf(m1, __shfl_xor(m1, off, 64));
        }
        float s0 = 0, s1 = 0;
        for (int i = start + lane; i < end; i += 64) {
            int s = csr_src[i];
            float2 l2 = *(const float2*)(el + s * 4 + hp * 2);
            s0 += expf(lrelu_f(l2.x + r2.x) - m0);
            s1 += expf(lrelu_f(l2.y + r2.y) - m1);
        }
        #pragma unroll
        for (int off = 1; off < 64; off <<= 1) {
            s0 += __shfl_xor(s0, off, 64);
            s1 += __shfl_xor(s1, off, 64);
        }
        float i0 = 1.0f / s0, i1 = 1.0f / s1;

        for (int base = start; base < end; base += 64) {
            int cnt = min(64, end - base);
            if (lane < cnt) {
                int s = csr_src[base + lane];
                float2 l2 = *(const float2*)(el + s * 4 + hp * 2);
                alds[wv][lane][0] = expf(lrelu_f(l2.x + r2.x) - m0) * i0;
                alds[wv][lane][1] = expf(lrelu_f(l2.y + r2.y) - m1) * i1;
                slds[wv][lane] = s;
            }
            __builtin_amdgcn_wave_barrier();
            for (int j = 0; j < cnt; ++j) {
                float a = alds[wv][j][hl];
                int  sj = slds[wv][j];
                unsigned f = *(const unsigned*)(fb + ((size_t)sj << 9) + boff);
                acc.x += __uint_as_float(f << 16) * a;
                acc.y += __uint_as_float(f & 0xffff0000u) * a;
            }
            __builtin_amdgcn_wave_barrier();
        }
        dg = 0;   // gather already done
    }

    // ---- batched gather (fast path): 8 edges per batch ----
    {
        int nfull = dg & ~7;
        for (int base = 0; base < nfull; base += 8) {
            float aa[8]; int ss[8];
            #pragma unroll
            for (int b = 0; b < 8; ++b) {
                aa[b] = alds[wv][base + b][hl];
                ss[b] = slds[wv][base + b];
            }
            unsigned ff[8];
            #pragma unroll
            for (int b = 0; b < 8; ++b)
                ff[b] = *(const unsigned*)(fb + ((size_t)ss[b] << 9) + boff);
            #pragma unroll
            for (int b = 0; b < 8; ++b) {
                acc.x += __uint_as_float(ff[b] << 16) * aa[b];
                acc.y += __uint_as_float(ff[b] & 0xffff0000u) * aa[b];
            }
        }
        for (int j = nfull; j < dg; ++j) {
            float a = alds[wv][j][hl];
            int  sj = slds[wv][j];
            unsigned f = *(const unsigned*)(fb + ((size_t)sj << 9) + boff);
            acc.x += __uint_as_float(f << 16) * a;
            acc.y += __uint_as_float(f & 0xffff0000u) * a;
        }
    }

    float2 bv = *(const float2*)(bias + head * 64 + (lane & 31) * 2);
    acc.x = elu_f(acc.x + bv.x);
    acc.y = elu_f(acc.y + bv.y);

    if (LAYER == 1) {
        ushort2 h2, l2;
        split_bf16(acc.x, h2.x, l2.x);
        split_bf16(acc.y, h2.y, l2.y);
        *(ushort2*)(ohi + (size_t)node * FDIM + head * 64 + (lane & 31) * 2) = h2;
        *(ushort2*)(olo + (size_t)node * FDIM + head * 64 + (lane & 31) * 2) = l2;
    } else {
        *(float2*)(outp + ((size_t)head * NNODES + node) * HID + (lane & 31) * 2) = acc;
    }
}

// ---------- launch ----------
extern "C" void kernel_launch(void* const* d_in, const int* in_sizes, int n_in,
                              void* d_out, int out_size, void* d_ws, size_t ws_size,
                              hipStream_t stream) {
    const float* x   = (const float*)d_in[0];
    const int*   src = (const int*)d_in[1];
    const int*   dst = (const int*)d_in[2];
    const float* W1  = (const float*)d_in[3];
    const float* al1 = (const float*)d_in[4];
    const float* ar1 = (const float*)d_in[5];
    const float* b1  = (const float*)d_in[6];
    const float* W2  = (const float*)d_in[7];
    const float* al2 = (const float*)d_in[8];
    const float* ar2 = (const float*)d_in[9];
    const float* b2  = (const float*)d_in[10];
    float* out = (float*)d_out;

    unsigned short* fbh  = (unsigned short*)d_ws;                    // NPAD*256 u16
    unsigned short* abhi = fbh  + (size_t)NPAD * FDIM;
    unsigned short* ablo = abhi + (size_t)NPAD * FDIM;
    unsigned short* wt1h = ablo + (size_t)NPAD * FDIM;               // 65536 each
    unsigned short* wt1l = wt1h + 65536;
    unsigned short* wt2h = wt1l + 65536;
    unsigned short* wt2l = wt2h + 65536;
    unsigned short* we1h = wt2l + 65536;                             // 4096 each
    unsigned short* we1l = we1h + 4096;
    unsigned short* we2h = we1l + 4096;
    unsigned short* we2l = we2h + 4096;
    float* el = (float*)(we2l + 4096);                               // NPAD*4
    float* er = el + (size_t)NPAD * HEADS;
    int* deg     = (int*)(er + (size_t)NPAD * HEADS);                // deg+cursor adjacent
    int* cursor  = deg + NNODES;
    int* incl    = cursor + NNODES;
    int* aux     = incl + NNODES;
    int* auxs    = aux + 256;
    int* csr_src = auxs + 256;

    const int edge_grid  = (NEDGES + 255) / 256;       // 3125
    const int node_grid  = (NNODES + 255) / 256;       // 196
    const int gat_grid   = (NNODES + 1) / 2;           // 25000
    const int gemm_grid  = NPAD / 64;                  // 782
    const int prep_grid  = WCONV_BLKS + WAL_BLKS + XCONV_BLKS + edge_grid;

    // ===== prep: weight/x converts + WAL/WAR + degree count =====
    hipMemsetAsync(deg, 0, 2 * NNODES * sizeof(int), stream);   // deg + cursor
    prep<<<prep_grid, 256, 0, stream>>>(x, abhi, ablo, W1, wt1h, wt1l,
                                        W2, wt2h, wt2l,
                                        al1, ar1, al2, ar2,
                                        we1h, we1l, we2h, we2l, dst, deg);

    // ===== CSR build =====
    scan_block<<<node_grid, 256, 0, stream>>>(deg, incl, aux, NNODES);
    scan_block<<<1, 256, 0, stream>>>(aux, auxs, nullptr, node_grid);
    fill_csr<<<edge_grid, 256, 0, stream>>>(src, dst, incl, auxs, deg, cursor, csr_src);

    // ===== layer 1 =====
    gemm_mfma<<<gemm_grid, 256, 0, stream>>>(abhi, ablo, wt1h, wt1l, we1h, we1l,
                                             fbh, el, er);
    gat_node<1><<<gat_grid, 256, 0, stream>>>(csr_src, incl, auxs, deg, el, er, fbh, b1,
                                              nullptr, abhi, ablo);

    // ===== layer 2 =====
    gemm_mfma<<<gemm_grid, 256, 0, stream>>>(abhi, ablo, wt2h, wt2l, we2h, we2l,
                                             fbh, el, er);
    gat_node<2><<<gat_grid, 256, 0, stream>>>(csr_src, incl, auxs, deg, el, er, fbh, b2,
                                              out, nullptr, nullptr);
}

// Round 8
// 380.355 us; speedup vs baseline: 1.0025x; 1.0025x over previous
//
#include <hip/hip_runtime.h>
#include <cstdint>
#include <cstddef>

#define NNODES 50000
#define NPAD   50048      // 782 * 64
#define NEDGES 800000
#define HEADS 4
#define HID 64
#define FDIM 256          // HEADS*HID == IN_DIM == 256
#define NEG_SLOPE 0.2f
#define GEMM_BLKS 782

typedef short bf16x8 __attribute__((ext_vector_type(8)));
typedef float f32x4  __attribute__((ext_vector_type(4)));

// ---------- helpers ----------
__device__ __forceinline__ float elu_f(float x) {
    return x > 0.0f ? x : expm1f(x);
}
__device__ __forceinline__ float lrelu_f(float x) {
    return x > 0.0f ? x : NEG_SLOPE * x;
}
__device__ __forceinline__ unsigned short f2bf_rn(float x) {
    unsigned u = __float_as_uint(x);
    unsigned r = u + 0x7FFFu + ((u >> 16) & 1u);
    return (unsigned short)(r >> 16);
}
__device__ __forceinline__ void split_bf16(float x, unsigned short& hi, unsigned short& lo) {
    hi = f2bf_rn(x);
    float fhi = __uint_as_float(((unsigned)hi) << 16);
    lo = f2bf_rn(x - fhi);
}

// ---------- fused prep ----------
#define WCONV_BLKS 32
#define WAL_BLKS   32
#define XCONV_BLKS 12512
__global__ __launch_bounds__(256) void prep(const float* __restrict__ x,
                                            unsigned short* __restrict__ abhi,
                                            unsigned short* __restrict__ ablo,
                                            const float* __restrict__ W1,
                                            unsigned short* __restrict__ wt1h,
                                            unsigned short* __restrict__ wt1l,
                                            const float* __restrict__ W2,
                                            unsigned short* __restrict__ wt2h,
                                            unsigned short* __restrict__ wt2l,
                                            const float* __restrict__ al1,
                                            const float* __restrict__ ar1,
                                            const float* __restrict__ al2,
                                            const float* __restrict__ ar2,
                                            unsigned short* __restrict__ we1h,
                                            unsigned short* __restrict__ we1l,
                                            unsigned short* __restrict__ we2h,
                                            unsigned short* __restrict__ we2l,
                                            const int* __restrict__ dst,
                                            int* __restrict__ deg) {
    __shared__ unsigned short wlds[2][16][264];
    int b = blockIdx.x;
    int tid = threadIdx.x;
    if (b < WCONV_BLKS) {
        int mat = b >> 4;
        const float* W = mat ? W2 : W1;
        unsigned short* wth = mat ? wt2h : wt1h;
        unsigned short* wtl = mat ? wt2l : wt1l;
        int k0 = (b & 15) * 16;
        #pragma unroll
        for (int i = 0; i < 16; ++i) {
            unsigned short h, l;
            split_bf16(W[(k0 + i) * 256 + tid], h, l);
            wlds[0][i][tid] = h;
            wlds[1][i][tid] = l;
        }
        __syncthreads();
        unsigned short vh[16], vl[16];
        #pragma unroll
        for (int j = 0; j < 16; ++j) { vh[j] = wlds[0][j][tid]; vl[j] = wlds[1][j][tid]; }
        *(uint4*)(wth + (size_t)tid * 256 + k0)     = *(uint4*)(vh);
        *(uint4*)(wth + (size_t)tid * 256 + k0 + 8) = *(uint4*)(vh + 8);
        *(uint4*)(wtl + (size_t)tid * 256 + k0)     = *(uint4*)(vl);
        *(uint4*)(wtl + (size_t)tid * 256 + k0 + 8) = *(uint4*)(vl + 8);
    } else if (b < WCONV_BLKS + WAL_BLKS) {
        int bb = b - WCONV_BLKS;
        int layer = bb >> 4;
        const float* W  = layer ? W2 : W1;
        const float* al = layer ? al2 : al1;
        const float* ar = layer ? ar2 : ar1;
        unsigned short* weh = layer ? we2h : we1h;
        unsigned short* wel = layer ? we2l : we1l;
        int t = (bb & 15) * 256 + tid;               // 0..4095
        int c = t >> 8, k = t & 255;                 // c: 0..15
        float val = 0.0f;
        if (c < 8) {
            int hh = c & 3;
            const float* av = (c < 4) ? al : ar;     // [4][64] flat
            const float* wr = W + k * 256 + hh * 64;
            #pragma unroll 16
            for (int d = 0; d < 64; ++d) val += wr[d] * av[hh * 64 + d];
        }
        unsigned short h, l;
        split_bf16(val, h, l);
        weh[c * 256 + k] = h;
        wel[c * 256 + k] = l;
    } else if (b < WCONV_BLKS + WAL_BLKS + XCONV_BLKS) {
        int i = (b - WCONV_BLKS - WAL_BLKS) * 256 + tid;   // float4 chunk id
        if (i >= NPAD * 64) return;
        int row = i >> 6;
        float4 v = {0, 0, 0, 0};
        if (row < NNODES) v = ((const float4*)x)[i];
        ushort4 h4, l4;
        split_bf16(v.x, h4.x, l4.x);
        split_bf16(v.y, h4.y, l4.y);
        split_bf16(v.z, h4.z, l4.z);
        split_bf16(v.w, h4.w, l4.w);
        ((ushort4*)abhi)[i] = h4;
        ((ushort4*)ablo)[i] = l4;
    } else {
        int e = (b - WCONV_BLKS - WAL_BLKS - XCONV_BLKS) * 256 + tid;
        if (e < NEDGES) atomicAdd(&deg[dst[e]], 1);
    }
}

// ---------- single-block full scan: deg -> {start,deg}, zero cursor ----------
__global__ __launch_bounds__(1024) void scan_full(const int* __restrict__ deg,
                                                  int2* __restrict__ startdeg,
                                                  int* __restrict__ cursor) {
    __shared__ int wsums[16];
    __shared__ int carry_s;
    if (threadIdx.x == 0) carry_s = 0;
    __syncthreads();
    int lane = threadIdx.x & 63, wid = threadIdx.x >> 6;
    for (int base = 0; base < NNODES; base += 1024) {
        int gid = base + threadIdx.x;
        int d = (gid < NNODES) ? deg[gid] : 0;
        int v = d;
        #pragma unroll
        for (int off = 1; off < 64; off <<= 1) {
            int t = __shfl_up(v, off, 64);
            if (lane >= off) v += t;
        }
        if (lane == 63) wsums[wid] = v;
        __syncthreads();
        int add = carry_s;
        for (int w = 0; w < wid; ++w) add += wsums[w];
        if (gid < NNODES) {
            startdeg[gid] = make_int2(v + add - d, d);
            cursor[gid] = 0;
        }
        __syncthreads();
        if (threadIdx.x == 0) {
            int tot = 0;
            for (int w = 0; w < 16; ++w) tot += wsums[w];
            carry_s += tot;
        }
        __syncthreads();
    }
}

// ---------- split-bf16 MFMA GEMM (+optional fused fill_csr blocks) ----------
#define CSTR 261
template <bool FILL>
__global__ __launch_bounds__(256, 2) void gemm_mfma(const unsigned short* __restrict__ Ahi,
                                                    const unsigned short* __restrict__ Alo,
                                                    const unsigned short* __restrict__ WThi,
                                                    const unsigned short* __restrict__ WTlo,
                                                    const unsigned short* __restrict__ WEhi,
                                                    const unsigned short* __restrict__ WElo,
                                                    unsigned short* __restrict__ fbh,
                                                    float* __restrict__ el,
                                                    float* __restrict__ er,
                                                    const int* __restrict__ src,
                                                    const int* __restrict__ dst,
                                                    const int2* __restrict__ startdeg,
                                                    int* __restrict__ cursor,
                                                    int* __restrict__ csr_src) {
    __shared__ char smem[66816];                     // A: 2x32768B; C: 64x261 f32
    const int tid  = threadIdx.x;

    if (FILL && blockIdx.x >= GEMM_BLKS) {
        int e = (blockIdx.x - GEMM_BLKS) * 256 + tid;
        if (e < NEDGES) {
            int s = src[e], d = dst[e];
            int pos = startdeg[d].x + atomicAdd(&cursor[d], 1);
            csr_src[pos] = s;
        }
        return;
    }

    const int lane = tid & 63;
    const int wave = tid >> 6;
    const int block_row = blockIdx.x * 64;

    // ---- stage A tile (hi+lo, 64 rows x 256 k, XOR-swizzled) ----
    const unsigned short* aplane[2] = {Ahi + (size_t)block_row * 256,
                                       Alo + (size_t)block_row * 256};
    #pragma unroll
    for (int i = 0; i < 16; ++i) {
        int chunk = i * 256 + tid;                   // 16B chunks, 0..4095
        int p   = chunk >> 11;
        int row = (chunk >> 5) & 63;
        int c   = chunk & 31;
        uint4 v = *(const uint4*)(aplane[p] + row * 256 + c * 8);
        int off = p * 32768 + row * 512 + ((c * 16) ^ ((row & 7) << 4));
        *(uint4*)(smem + off) = v;
    }
    __syncthreads();

    // ---- K-loop ----
    f32x4 acc[4][4];
    f32x4 acc_e = (f32x4){0, 0, 0, 0};               // extra el/er tile (m = wave)
    #pragma unroll
    for (int m = 0; m < 4; ++m)
        #pragma unroll
        for (int n = 0; n < 4; ++n)
            acc[m][n] = (f32x4){0, 0, 0, 0};

    const int g = lane >> 4;                         // 0..3
    int arow[4], aswz[4];
    #pragma unroll
    for (int m = 0; m < 4; ++m) {
        int row = m * 16 + (lane & 15);
        arow[m] = row * 512;
        aswz[m] = (row & 7) << 4;
    }
    const unsigned short* wb[2][4];
    #pragma unroll
    for (int n = 0; n < 4; ++n) {
        int col = wave * 64 + n * 16 + (lane & 15);
        wb[0][n] = WThi + col * 256 + g * 8;
        wb[1][n] = WTlo + col * 256 + g * 8;
    }
    const unsigned short* we_h = WEhi + (lane & 15) * 256 + g * 8;
    const unsigned short* we_l = WElo + (lane & 15) * 256 + g * 8;

    #pragma unroll
    for (int t = 0; t < 8; ++t) {
        bf16x8 ah[4], al_[4], wh[4], wl[4];
        int koff = t * 64 + g * 16;
        #pragma unroll
        for (int m = 0; m < 4; ++m) {
            ah[m]  = *(const bf16x8*)(smem + arow[m] + (koff ^ aswz[m]));
            al_[m] = *(const bf16x8*)(smem + 32768 + arow[m] + (koff ^ aswz[m]));
        }
        #pragma unroll
        for (int n = 0; n < 4; ++n) {
            wh[n] = *(const bf16x8*)(wb[0][n] + t * 32);
            wl[n] = *(const bf16x8*)(wb[1][n] + t * 32);
        }
        #pragma unroll
        for (int m = 0; m < 4; ++m)
            #pragma unroll
            for (int n = 0; n < 4; ++n) {
                acc[m][n] = __builtin_amdgcn_mfma_f32_16x16x32_bf16(ah[m],  wh[n], acc[m][n], 0, 0, 0);
                acc[m][n] = __builtin_amdgcn_mfma_f32_16x16x32_bf16(ah[m],  wl[n], acc[m][n], 0, 0, 0);
                acc[m][n] = __builtin_amdgcn_mfma_f32_16x16x32_bf16(al_[m], wh[n], acc[m][n], 0, 0, 0);
            }
        bf16x8 ahw = (wave == 0) ? ah[0] : (wave == 1) ? ah[1] : (wave == 2) ? ah[2] : ah[3];
        bf16x8 alw = (wave == 0) ? al_[0] : (wave == 1) ? al_[1] : (wave == 2) ? al_[2] : al_[3];
        bf16x8 eh = *(const bf16x8*)(we_h + t * 32);
        bf16x8 el8 = *(const bf16x8*)(we_l + t * 32);
        acc_e = __builtin_amdgcn_mfma_f32_16x16x32_bf16(ahw, eh,  acc_e, 0, 0, 0);
        acc_e = __builtin_amdgcn_mfma_f32_16x16x32_bf16(ahw, el8, acc_e, 0, 0, 0);
        acc_e = __builtin_amdgcn_mfma_f32_16x16x32_bf16(alw, eh,  acc_e, 0, 0, 0);
    }

    // ---- el/er direct store ----
    {
        int c = lane & 15, rg = lane >> 4;
        if (c < 8) {
            float* dp = (c < 4) ? el : er;
            int hh = c & 3;
            #pragma unroll
            for (int r = 0; r < 4; ++r) {
                int node = block_row + wave * 16 + rg * 4 + r;
                dp[node * 4 + hh] = acc_e[r];
            }
        }
    }

    // ---- epilogue: C -> LDS (row-major [64][261]) ----
    __syncthreads();                                 // A planes dead
    float* C = (float*)smem;
    #pragma unroll
    for (int m = 0; m < 4; ++m) {
        int r0 = m * 16 + g * 4;
        #pragma unroll
        for (int n = 0; n < 4; ++n) {
            int col = wave * 64 + n * 16 + (lane & 15);
            C[(r0 + 0) * CSTR + col] = acc[m][n][0];
            C[(r0 + 1) * CSTR + col] = acc[m][n][1];
            C[(r0 + 2) * CSTR + col] = acc[m][n][2];
            C[(r0 + 3) * CSTR + col] = acc[m][n][3];
        }
    }
    __syncthreads();

    // coalesced bf16-hi feat write
    #pragma unroll
    for (int i = 0; i < 8; ++i) {
        int flat = i * 256 + tid;                    // 0..2047
        int r  = flat >> 5;
        int c8 = flat & 31;
        const float* cp = C + r * CSTR + c8 * 8;
        unsigned short us[8];
        #pragma unroll
        for (int k = 0; k < 8; ++k) us[k] = f2bf_rn(cp[k]);
        uint4 pk;
        pk.x = (unsigned)us[0] | ((unsigned)us[1] << 16);
        pk.y = (unsigned)us[2] | ((unsigned)us[3] << 16);
        pk.z = (unsigned)us[4] | ((unsigned)us[5] << 16);
        pk.w = (unsigned)us[6] | ((unsigned)us[7] << 16);
        *(uint4*)(fbh + (size_t)(block_row + r) * FDIM + c8 * 8) = pk;
    }
}

// ---------- fused per-node softmax + aggregate + bias + ELU (r4 shape) ----------
// one 64-lane wave per dst node; 4 waves per block; alpha staged in LDS.
// LAYER==1: write bf16 hi/lo planes; LAYER==2: f32 out [head][node][64]
template <int LAYER>
__global__ __launch_bounds__(256, 8) void gat_node(const int* __restrict__ csr_src,
                                                   const int2* __restrict__ startdeg,
                                                   const float* __restrict__ el,
                                                   const float* __restrict__ er,
                                                   const unsigned short* __restrict__ fbh,
                                                   const float* __restrict__ bias,
                                                   float* __restrict__ outp,
                                                   unsigned short* __restrict__ ohi,
                                                   unsigned short* __restrict__ olo) {
    __shared__ float alds[4][64][4];
    __shared__ int   slds[4][64];
    int wv   = threadIdx.x >> 6;
    int node = blockIdx.x * 4 + wv;
    if (node >= NNODES) return;
    int lane = threadIdx.x & 63;
    int h = lane >> 4;

    int2 sd   = startdeg[node];
    int start = sd.x, dg = sd.y, end = start + dg;
    float4 r4 = ((const float4*)er)[node];
    float4 acc = {0, 0, 0, 0};
    const char* fb = (const char*)fbh;
    const int laneoff = lane * 8;                    // byte offset within 512B row

    if (dg <= 64) {
        // ---- fast path: all scores in registers, single pass ----
        bool act = lane < dg;
        int s = act ? csr_src[start + lane] : 0;
        float4 l4 = ((const float4*)el)[s];
        float c0 = act ? lrelu_f(l4.x + r4.x) : -INFINITY;
        float c1 = act ? lrelu_f(l4.y + r4.y) : -INFINITY;
        float c2 = act ? lrelu_f(l4.z + r4.z) : -INFINITY;
        float c3 = act ? lrelu_f(l4.w + r4.w) : -INFINITY;
        float m0 = c0, m1 = c1, m2 = c2, m3 = c3;
        #pragma unroll
        for (int off = 1; off < 64; off <<= 1) {
            m0 = fmaxf(m0, __shfl_xor(m0, off, 64));
            m1 = fmaxf(m1, __shfl_xor(m1, off, 64));
            m2 = fmaxf(m2, __shfl_xor(m2, off, 64));
            m3 = fmaxf(m3, __shfl_xor(m3, off, 64));
        }
        float p0 = act ? expf(c0 - m0) : 0.0f;
        float p1 = act ? expf(c1 - m1) : 0.0f;
        float p2 = act ? expf(c2 - m2) : 0.0f;
        float p3 = act ? expf(c3 - m3) : 0.0f;
        float s0 = p0, s1 = p1, s2 = p2, s3 = p3;
        #pragma unroll
        for (int off = 1; off < 64; off <<= 1) {
            s0 += __shfl_xor(s0, off, 64);
            s1 += __shfl_xor(s1, off, 64);
            s2 += __shfl_xor(s2, off, 64);
            s3 += __shfl_xor(s3, off, 64);
        }
        float4 a4 = {p0 / s0, p1 / s1, p2 / s2, p3 / s3};
        *(float4*)(&alds[wv][lane][0]) = a4;
        slds[wv][lane] = s;
        __builtin_amdgcn_wave_barrier();

        #pragma unroll 4
        for (int j = 0; j < dg; ++j) {
            float a = alds[wv][j][h];
            int  sj = slds[wv][j];
            uint2 f = *(const uint2*)(fb + ((size_t)sj << 9) + laneoff);
            acc.x += __uint_as_float(f.x << 16) * a;
            acc.y += __uint_as_float(f.x & 0xffff0000u) * a;
            acc.z += __uint_as_float(f.y << 16) * a;
            acc.w += __uint_as_float(f.y & 0xffff0000u) * a;
        }
    } else {
        // ---- slow path (deg > 64): two-pass max/denom, chunked gather ----
        float m0 = -INFINITY, m1 = -INFINITY, m2 = -INFINITY, m3 = -INFINITY;
        for (int i = start + lane; i < end; i += 64) {
            int s = csr_src[i];
            float4 l4 = ((const float4*)el)[s];
            m0 = fmaxf(m0, lrelu_f(l4.x + r4.x));
            m1 = fmaxf(m1, lrelu_f(l4.y + r4.y));
            m2 = fmaxf(m2, lrelu_f(l4.z + r4.z));
            m3 = fmaxf(m3, lrelu_f(l4.w + r4.w));
        }
        #pragma unroll
        for (int off = 1; off < 64; off <<= 1) {
            m0 = fmaxf(m0, __shfl_xor(m0, off, 64));
            m1 = fmaxf(m1, __shfl_xor(m1, off, 64));
            m2 = fmaxf(m2, __shfl_xor(m2, off, 64));
            m3 = fmaxf(m3, __shfl_xor(m3, off, 64));
        }
        float s0 = 0, s1 = 0, s2 = 0, s3 = 0;
        for (int i = start + lane; i < end; i += 64) {
            int s = csr_src[i];
            float4 l4 = ((const float4*)el)[s];
            s0 += expf(lrelu_f(l4.x + r4.x) - m0);
            s1 += expf(lrelu_f(l4.y + r4.y) - m1);
            s2 += expf(lrelu_f(l4.z + r4.z) - m2);
            s3 += expf(lrelu_f(l4.w + r4.w) - m3);
        }
        #pragma unroll
        for (int off = 1; off < 64; off <<= 1) {
            s0 += __shfl_xor(s0, off, 64);
            s1 += __shfl_xor(s1, off, 64);
            s2 += __shfl_xor(s2, off, 64);
            s3 += __shfl_xor(s3, off, 64);
        }
        float i0 = 1.0f / s0, i1 = 1.0f / s1, i2 = 1.0f / s2, i3 = 1.0f / s3;

        for (int base = start; base < end; base += 64) {
            int cnt = min(64, end - base);
            if (lane < cnt) {
                int s = csr_src[base + lane];
                float4 l4 = ((const float4*)el)[s];
                float4 a4;
                a4.x = expf(lrelu_f(l4.x + r4.x) - m0) * i0;
                a4.y = expf(lrelu_f(l4.y + r4.y) - m1) * i1;
                a4.z = expf(lrelu_f(l4.z + r4.z) - m2) * i2;
                a4.w = expf(lrelu_f(l4.w + r4.w) - m3) * i3;
                *(float4*)(&alds[wv][lane][0]) = a4;
                slds[wv][lane] = s;
            }
            __builtin_amdgcn_wave_barrier();
            for (int j = 0; j < cnt; ++j) {
                float a = alds[wv][j][h];
                int  sj = slds[wv][j];
                uint2 f = *(const uint2*)(fb + ((size_t)sj << 9) + laneoff);
                acc.x += __uint_as_float(f.x << 16) * a;
                acc.y += __uint_as_float(f.x & 0xffff0000u) * a;
                acc.z += __uint_as_float(f.y << 16) * a;
                acc.w += __uint_as_float(f.y & 0xffff0000u) * a;
            }
            __builtin_amdgcn_wave_barrier();
        }
    }

    float4 b = ((const float4*)bias)[lane];
    acc.x = elu_f(acc.x + b.x);
    acc.y = elu_f(acc.y + b.y);
    acc.z = elu_f(acc.z + b.z);
    acc.w = elu_f(acc.w + b.w);

    if (LAYER == 1) {
        ushort4 h4, l4;
        split_bf16(acc.x, h4.x, l4.x);
        split_bf16(acc.y, h4.y, l4.y);
        split_bf16(acc.z, h4.z, l4.z);
        split_bf16(acc.w, h4.w, l4.w);
        *(ushort4*)(ohi + (size_t)node * FDIM + lane * 4) = h4;
        *(ushort4*)(olo + (size_t)node * FDIM + lane * 4) = l4;
    } else {
        *(float4*)(outp + ((size_t)h * NNODES + node) * HID + (lane & 15) * 4) = acc;
    }
}

// ---------- launch ----------
extern "C" void kernel_launch(void* const* d_in, const int* in_sizes, int n_in,
                              void* d_out, int out_size, void* d_ws, size_t ws_size,
                              hipStream_t stream) {
    const float* x   = (const float*)d_in[0];
    const int*   src = (const int*)d_in[1];
    const int*   dst = (const int*)d_in[2];
    const float* W1  = (const float*)d_in[3];
    const float* al1 = (const float*)d_in[4];
    const float* ar1 = (const float*)d_in[5];
    const float* b1  = (const float*)d_in[6];
    const float* W2  = (const float*)d_in[7];
    const float* al2 = (const float*)d_in[8];
    const float* ar2 = (const float*)d_in[9];
    const float* b2  = (const float*)d_in[10];
    float* out = (float*)d_out;

    unsigned short* fbh  = (unsigned short*)d_ws;                    // NPAD*256 u16
    unsigned short* abhi = fbh  + (size_t)NPAD * FDIM;
    unsigned short* ablo = abhi + (size_t)NPAD * FDIM;
    unsigned short* wt1h = ablo + (size_t)NPAD * FDIM;               // 65536 each
    unsigned short* wt1l = wt1h + 65536;
    unsigned short* wt2h = wt1l + 65536;
    unsigned short* wt2l = wt2h + 65536;
    unsigned short* we1h = wt2l + 65536;                             // 4096 each
    unsigned short* we1l = we1h + 4096;
    unsigned short* we2h = we1l + 4096;
    unsigned short* we2l = we2h + 4096;
    float* el = (float*)(we2l + 4096);                               // NPAD*4
    float* er = el + (size_t)NPAD * HEADS;
    int*  deg      = (int*)(er + (size_t)NPAD * HEADS);
    int*  cursor   = deg + NNODES;
    int2* startdeg = (int2*)(cursor + NNODES);                       // NNODES int2
    int*  csr_src  = (int*)(startdeg + NNODES);

    const int edge_grid  = (NEDGES + 255) / 256;       // 3125
    const int gat_grid   = (NNODES + 3) / 4;           // 12500
    const int prep_grid  = WCONV_BLKS + WAL_BLKS + XCONV_BLKS + edge_grid;

    // ===== prep: converts + WAL/WAR + degree count =====
    hipMemsetAsync(deg, 0, NNODES * sizeof(int), stream);
    prep<<<prep_grid, 256, 0, stream>>>(x, abhi, ablo, W1, wt1h, wt1l,
                                        W2, wt2h, wt2l,
                                        al1, ar1, al2, ar2,
                                        we1h, we1l, we2h, we2l, dst, deg);

    // ===== CSR scan (single block) =====
    scan_full<<<1, 1024, 0, stream>>>(deg, startdeg, cursor);

    // ===== layer 1 GEMM + fused CSR fill =====
    gemm_mfma<true><<<GEMM_BLKS + edge_grid, 256, 0, stream>>>(
        abhi, ablo, wt1h, wt1l, we1h, we1l, fbh, el, er,
        src, dst, startdeg, cursor, csr_src);
    gat_node<1><<<gat_grid, 256, 0, stream>>>(csr_src, startdeg, el, er, fbh, b1,
                                              nullptr, abhi, ablo);

    // ===== layer 2 =====
    gemm_mfma<false><<<GEMM_BLKS, 256, 0, stream>>>(
        abhi, ablo, wt2h, wt2l, we2h, we2l, fbh, el, er,
        nullptr, nullptr, nullptr, nullptr, nullptr);
    gat_node<2><<<gat_grid, 256, 0, stream>>>(csr_src, startdeg, el, er, fbh, b2,
                                              out, nullptr, nullptr);
}